// Round 1
// baseline (74.684 us; speedup 1.0000x reference)
//
#include <hip/hip_runtime.h>

// DistMaps: out[b,g,r,c] = tanh(2*sqrt(min_p ((r-pr)/5)^2 + ((c-pc)/5)^2))
//   x: (8,3,512,512) fp32  -- shape only, never read
//   coords: (8,48,3) fp32  -- 2 groups x 24 clicks; invalid iff max(r,c)<0
//   out: (8,2,512,512) fp32
#define HH 512
#define WW 512
#define PP 24
#define NPT 48
#define TH 32    // tile rows
#define TW 128   // tile cols
// Cull radius (pixels): beyond 16 px, tanh(2*d/5) >= tanh(6.4) = 1-5.5e-6 -> 1.0f
#define RCUT2 256.0f

__device__ __forceinline__ float tanh2sqrt(float m) {
    // tanh(2*sqrt(m)) = (1-e)/(1+e), e = exp(-4*sqrt(m)); exact 1.0 on underflow
    float s = __builtin_amdgcn_sqrtf(m);
    float e = __expf(-4.0f * s);
    return __fdividef(1.0f - e, 1.0f + e);
}

__global__ __launch_bounds__(256) void DistMaps_37434934952233_kernel(
    const float* __restrict__ coords, float* __restrict__ out)
{
    const int blk  = blockIdx.x;
    const int map  = blk >> 6;         // b*2+g, 16 maps
    const int tile = blk & 63;         // 64 tiles/map: 16 tile-rows x 4 tile-cols
    const int r0   = (tile >> 2) << 5; // *TH
    const int c0   = (tile & 3) << 7;  // *TW
    const int b    = map >> 1;
    const int g    = map & 1;

    constexpr float INV_SCALE = 1.0f / 5.0f;

    __shared__ float npr[PP];
    __shared__ float npc[PP];
    __shared__ int   nnear;

    const int t = threadIdx.x;

    // Wave 0 does the cull + compaction via ballot (no atomics, single barrier).
    if (t < 64) {
        bool near = false;
        float pr = 0.0f, pc = 0.0f;
        if (t < PP) {
            const float* cp = coords + (size_t)(b * NPT + g * PP + t) * 3;
            pr = cp[0];
            pc = cp[1];
            const bool valid = fmaxf(pr, pc) >= 0.0f;  // reference: invalid iff max<0
            // min distance^2 from point to this tile's pixel rectangle
            const float dr = fmaxf(0.0f, fmaxf((float)r0 - pr, pr - (float)(r0 + TH - 1)));
            const float dc = fmaxf(0.0f, fmaxf((float)c0 - pc, pc - (float)(c0 + TW - 1)));
            near = valid && (dr * dr + dc * dc) <= RCUT2;
        }
        const unsigned long long m = __ballot(near);
        if (near) {
            const int i = __popcll(m & ((1ull << t) - 1ull));
            npr[i] = pr * INV_SCALE;
            npc[i] = pc * INV_SCALE;
        }
        if (t == 0) nnear = (int)__popcll(m);
    }
    __syncthreads();

    // Each thread: rows rb, rb+8, rb+16, rb+24 ; 4 consecutive cols at cc.
    const int rb = r0 + (t >> 5);
    const int cc = c0 + ((t & 31) << 2);
    const int n  = nnear;

    float* op = out + ((size_t)map * HH + rb) * WW + cc;

    if (n == 0) {
        const float4 one = make_float4(1.0f, 1.0f, 1.0f, 1.0f);
        #pragma unroll
        for (int k = 0; k < 4; ++k)
            *reinterpret_cast<float4*>(op + (size_t)k * 8 * WW) = one;
        return;
    }

    const float cs0 = (float)cc * INV_SCALE;
    const float cs1 = cs0 + INV_SCALE;
    const float cs2 = cs0 + 2.0f * INV_SCALE;
    const float cs3 = cs0 + 3.0f * INV_SCALE;

    float rs[4];
    #pragma unroll
    for (int k = 0; k < 4; ++k) rs[k] = (float)(rb + 8 * k) * INV_SCALE;

    float mm[4][4];
    #pragma unroll
    for (int k = 0; k < 4; ++k)
        #pragma unroll
        for (int j = 0; j < 4; ++j) mm[k][j] = 1e30f;

    for (int p = 0; p < n; ++p) {
        const float pr = npr[p];
        const float pc = npc[p];
        const float d0 = cs0 - pc, d1 = cs1 - pc, d2 = cs2 - pc, d3 = cs3 - pc;
        const float e0 = d0 * d0, e1 = d1 * d1, e2 = d2 * d2, e3 = d3 * d3;
        #pragma unroll
        for (int k = 0; k < 4; ++k) {
            const float dr  = rs[k] - pr;
            const float dr2 = dr * dr;
            mm[k][0] = fminf(mm[k][0], e0 + dr2);
            mm[k][1] = fminf(mm[k][1], e1 + dr2);
            mm[k][2] = fminf(mm[k][2], e2 + dr2);
            mm[k][3] = fminf(mm[k][3], e3 + dr2);
        }
    }

    #pragma unroll
    for (int k = 0; k < 4; ++k) {
        float4 o;
        o.x = tanh2sqrt(mm[k][0]);
        o.y = tanh2sqrt(mm[k][1]);
        o.z = tanh2sqrt(mm[k][2]);
        o.w = tanh2sqrt(mm[k][3]);
        *reinterpret_cast<float4*>(op + (size_t)k * 8 * WW) = o;
    }
}

extern "C" void kernel_launch(void* const* d_in, const int* in_sizes, int n_in,
                              void* d_out, int out_size, void* d_ws, size_t ws_size,
                              hipStream_t stream) {
    (void)in_sizes; (void)n_in; (void)d_ws; (void)ws_size; (void)out_size;
    const float* coords = (const float*)d_in[1];   // d_in[0] = x (unused)
    float* out = (float*)d_out;
    DistMaps_37434934952233_kernel<<<16 * 64, 256, 0, stream>>>(coords, out);
}